// Round 7
// baseline (324.615 us; speedup 1.0000x reference)
//
#include <hip/hip_runtime.h>

// GCN: 3 x (gather-aggregate via CSR -> GEMM(+bias,+relu))
// R1: CSR gather aggregation (no fp32 atomics).
// R2: layers 1&2 GEMM -> bf16 MFMA, global_load_lds(16) staging, XOR swizzle.
// R3: bf16 end-to-end; layer-3 GEMM -> bf16 MFMA; fused epilogues.
// R4: double-buffered LDS in MFMA GEMMs; XCD-partitioned gather. (GEMM 43us)
// R5: XCD grid swizzle -> REGRESSED. R6: BN=64+vmcnt(3) -> REGRESSED.
// R7: 128x128 tile, 512-thread blocks (8 waves): GEMM ~38us. Kept.
// R8: k_aggb unroll x4; fuse 3x k_wconv; fold k_norm into k_scan.
// R9: k_aggb unroll x8; GEMM XCD A-reuse grouping; k_agg64 unroll x4.
//     296.8 -> 277.7 us. BEST so far.
// R10: GEMM 128x256 tile -> REGRESSED (1.25 blk/CU, occupancy cliff).
// R11: aggb half-split isolated ~-6us -> reverted (R9 aggb is optimum).
// R12: counted-vmcnt triple-buffer -> REGRESSED (41-45us; pinned waitcnt
//      defeats compiler sched in 2-phase loops, matches guide m131/m141).
// R13: 4-wave 64x64 wave-tile -> REGRESSED (48us): grid 640 caps blocks/CU
//      at 2.5, so 256-thr blocks halve waves/CU (20 -> 10); wave-level TLP
//      is what hides the per-step stall. Keep 512-thr blocks.
// R14: BK=64 (untested axis: barrier COUNT). 16 K-steps instead of 32 --
//      halves per-step drain/barrier events, same staged bytes, 2x MFMA
//      per step per wave (16 MFMA : 12 ds_read : 4 gl_lds). LDS 64KB ->
//      2 blk/CU (accepted; stall-count reduction should dominate).
//      [R15 = resubmit: round-6 bench was an infra failure, no data.]
constexpr int NN   = 10000;
constexpr int NE   = 160000;
constexpr int F    = 1024;
constexpr int C3   = 64;
constexpr int MPAD = 10240;   // 80 * 128

typedef __attribute__((ext_vector_type(8))) short short8;
typedef __attribute__((ext_vector_type(8))) unsigned short ushort8v;
typedef __attribute__((ext_vector_type(4))) float floatx4;

__device__ __forceinline__ unsigned short f2bf(float f) {
    union { float f; unsigned u; } v; v.f = f;
    unsigned r = v.u + 0x7fff + ((v.u >> 16) & 1);   // RNE
    return (unsigned short)(r >> 16);
}
__device__ __forceinline__ float bf2f(unsigned short u) {
    union { unsigned u; float f; } v; v.u = ((unsigned)u) << 16;
    return v.f;
}

__device__ __forceinline__ void gl_lds16(const void* g, void* l) {
    __builtin_amdgcn_global_load_lds(
        (const __attribute__((address_space(1))) unsigned int*)g,
        (__attribute__((address_space(3))) unsigned int*)l, 16, 0, 0);
}

// ---- CSR build ------------------------------------------------------------

__global__ __launch_bounds__(256) void k_degree(const int* __restrict__ src,
                                                const int* __restrict__ dst,
                                                int* __restrict__ deg_out,
                                                int* __restrict__ deg_in) {
    int e = blockIdx.x * 256 + threadIdx.x;
    if (e < NE) {
        atomicAdd(&deg_out[src[e]], 1);
        atomicAdd(&deg_in[dst[e]], 1);
    }
}

// single-block: exclusive scan of deg_in -> row_ptr/cursor, plus both norms
// (1024 threads x CH=10 covers 10240 == MPAD).
__global__ __launch_bounds__(1024) void k_scan(const int* __restrict__ deg_in,
                                               const int* __restrict__ deg_out,
                                               int* __restrict__ row_ptr,
                                               int* __restrict__ cursor,
                                               float* __restrict__ norm_src,
                                               float* __restrict__ norm_dst) {
    constexpr int CH = 10;
    __shared__ int sums[1024];
    const int tid = threadIdx.x;
    int local[CH];
    int tsum = 0;
#pragma unroll
    for (int j = 0; j < CH; ++j) {
        int idx = tid * CH + j;
        int v = (idx < NN) ? deg_in[idx] : 0;
        local[j] = v;
        tsum += v;
        if (idx < MPAD) {   // fused norm computation (padded rows: deg=0 -> 1.0)
            norm_src[idx] = rsqrtf(fmaxf((float)deg_out[idx], 1.0f));
            norm_dst[idx] = rsqrtf(fmaxf((float)deg_in[idx], 1.0f));
        }
    }
    sums[tid] = tsum;
    __syncthreads();
    for (int off = 1; off < 1024; off <<= 1) {
        int v = (tid >= off) ? sums[tid - off] : 0;
        __syncthreads();
        sums[tid] += v;
        __syncthreads();
    }
    int run = sums[tid] - tsum;
#pragma unroll
    for (int j = 0; j < CH; ++j) {
        int idx = tid * CH + j;
        if (idx < NN) {
            row_ptr[idx] = run;
            cursor[idx]  = run;
        }
        run += local[j];
    }
    if (tid == 1023) row_ptr[NN] = sums[1023];
}

__global__ __launch_bounds__(256) void k_bucket(const int* __restrict__ src,
                                                const int* __restrict__ dst,
                                                int* __restrict__ cursor,
                                                int* __restrict__ csr_src) {
    int e = blockIdx.x * 256 + threadIdx.x;
    if (e < NE) {
        int slot = atomicAdd(&cursor[dst[e]], 1);
        csr_src[slot] = src[e];
    }
}

// ---- fused weight transpose+convert: all three W -> Wt bf16 [n][k=F] ------
// blocks 0..1023: W1; 1024..2047: W2; 2048..2111: W3 (N=C3).
__global__ __launch_bounds__(256) void k_wconv_all(const float* __restrict__ W1,
                                                   const float* __restrict__ W2,
                                                   const float* __restrict__ W3,
                                                   unsigned short* __restrict__ Wt1,
                                                   unsigned short* __restrict__ Wt2,
                                                   unsigned short* __restrict__ Wt3) {
    __shared__ float tile[32][33];
    const float* W; unsigned short* Wt; int N, n0, k0;
    int b = blockIdx.x;
    if (b < 1024)      { W = W1; Wt = Wt1; N = F;  n0 = (b & 31) * 32;          k0 = (b >> 5) * 32; }
    else if (b < 2048) { b -= 1024; W = W2; Wt = Wt2; N = F;  n0 = (b & 31) * 32; k0 = (b >> 5) * 32; }
    else               { b -= 2048; W = W3; Wt = Wt3; N = C3; n0 = (b & 1) * 32;  k0 = (b >> 1) * 32; }
    const int tx = threadIdx.x & 31, ty = threadIdx.x >> 5;   // 32 x 8
#pragma unroll
    for (int i = 0; i < 32; i += 8)
        tile[ty + i][tx] = W[(size_t)(k0 + ty + i) * N + n0 + tx];  // [k][n]
    __syncthreads();
#pragma unroll
    for (int i = 0; i < 32; i += 8)
        Wt[(size_t)(n0 + ty + i) * F + k0 + tx] = f2bf(tile[tx][ty + i]);
}

// ---- h -> bf16 with norm_src fold: hb[v][f] = bf16(ns[v]*h[v][f]) ---------

__global__ __launch_bounds__(256) void k_hcvt(const float* __restrict__ h,
                                              const float* __restrict__ norm_src,
                                              unsigned short* __restrict__ hb) {
    int idx = blockIdx.x * 256 + threadIdx.x;     // NN*128 total
    int v = idx >> 7, f8 = (idx & 127) * 8;
    float ns = norm_src[v];
    const float4 a = *(const float4*)(h + (size_t)v * F + f8);
    const float4 b = *(const float4*)(h + (size_t)v * F + f8 + 4);
    ushort8v o;
    o[0] = f2bf(ns * a.x); o[1] = f2bf(ns * a.y);
    o[2] = f2bf(ns * a.z); o[3] = f2bf(ns * a.w);
    o[4] = f2bf(ns * b.x); o[5] = f2bf(ns * b.y);
    o[6] = f2bf(ns * b.z); o[7] = f2bf(ns * b.w);
    *(ushort8v*)(hb + (size_t)v * F + f8) = o;
}

// ---- aggregation: bf16 in, fp32 accumulate, bf16 out ----------------------
// XCD-partitioned: chunk c = blockIdx%8 -> per-XCD slice 2.56 MB < 4 MB L2.
// 16 nodes per block, 16 lanes x 8 bf16 (16B) per node. Edge loop unroll x8
// (8 idx loads + 8 gathers in flight -- gather is L2-latency-chain-bound).
// R9 config -- R10/R11 showed the half-split variant is ~6us worse.
__global__ __launch_bounds__(256) void k_aggb(const unsigned short* __restrict__ xb,
                                              const int* __restrict__ row_ptr,
                                              const int* __restrict__ csr_src,
                                              unsigned short* __restrict__ aggb) {
    const int c = blockIdx.x & 7;                       // feature chunk -> XCD
    const int g = blockIdx.x >> 3;                      // node group
    const int v = g * 16 + (threadIdx.x >> 4);          // 625*16 == NN exactly
    const int f8 = c * 128 + (threadIdx.x & 15) * 8;
    const unsigned short* xr = xb + f8;
    const int lo = row_ptr[v], hi = row_ptr[v + 1];
    float acc[8] = {0.f, 0.f, 0.f, 0.f, 0.f, 0.f, 0.f, 0.f};
    int i = lo;
    for (; i + 8 <= hi; i += 8) {
        int s0 = csr_src[i],     s1 = csr_src[i + 1];
        int s2 = csr_src[i + 2], s3 = csr_src[i + 3];
        int s4 = csr_src[i + 4], s5 = csr_src[i + 5];
        int s6 = csr_src[i + 6], s7 = csr_src[i + 7];
        ushort8v x0 = *(const ushort8v*)(xr + (size_t)s0 * F);
        ushort8v x1 = *(const ushort8v*)(xr + (size_t)s1 * F);
        ushort8v x2 = *(const ushort8v*)(xr + (size_t)s2 * F);
        ushort8v x3 = *(const ushort8v*)(xr + (size_t)s3 * F);
        ushort8v x4 = *(const ushort8v*)(xr + (size_t)s4 * F);
        ushort8v x5 = *(const ushort8v*)(xr + (size_t)s5 * F);
        ushort8v x6 = *(const ushort8v*)(xr + (size_t)s6 * F);
        ushort8v x7 = *(const ushort8v*)(xr + (size_t)s7 * F);
#pragma unroll
        for (int j = 0; j < 8; ++j) acc[j] += bf2f(x0[j]);
#pragma unroll
        for (int j = 0; j < 8; ++j) acc[j] += bf2f(x1[j]);
#pragma unroll
        for (int j = 0; j < 8; ++j) acc[j] += bf2f(x2[j]);
#pragma unroll
        for (int j = 0; j < 8; ++j) acc[j] += bf2f(x3[j]);
#pragma unroll
        for (int j = 0; j < 8; ++j) acc[j] += bf2f(x4[j]);
#pragma unroll
        for (int j = 0; j < 8; ++j) acc[j] += bf2f(x5[j]);
#pragma unroll
        for (int j = 0; j < 8; ++j) acc[j] += bf2f(x6[j]);
#pragma unroll
        for (int j = 0; j < 8; ++j) acc[j] += bf2f(x7[j]);
    }
    for (; i < hi; ++i) {
        int s = csr_src[i];
        ushort8v xv = *(const ushort8v*)(xr + (size_t)s * F);
#pragma unroll
        for (int j = 0; j < 8; ++j) acc[j] += bf2f(xv[j]);
    }
    ushort8v o;
#pragma unroll
    for (int j = 0; j < 8; ++j) o[j] = f2bf(acc[j]);
    *(ushort8v*)(aggb + (size_t)v * F + f8) = o;
}

// layer-3 aggregation over z3 (fp32, 64 feats), fused nd/bias, writes d_out.
// 16 nodes per block, 16 lanes x float4 per node. R9: unroll x4.
__global__ __launch_bounds__(256) void k_agg64(const float* __restrict__ z,
                                               const int* __restrict__ row_ptr,
                                               const int* __restrict__ csr_src,
                                               const float* __restrict__ norm_dst,
                                               const float* __restrict__ b3,
                                               float* __restrict__ out) {
    const int v = blockIdx.x * 16 + (threadIdx.x >> 4);
    if (v >= NN) return;
    const int f4 = (threadIdx.x & 15) * 4;
    const int lo = row_ptr[v], hi = row_ptr[v + 1];
    float4 acc = {0.f, 0.f, 0.f, 0.f};
    int i = lo;
    for (; i + 4 <= hi; i += 4) {
        int s0 = csr_src[i],     s1 = csr_src[i + 1];
        int s2 = csr_src[i + 2], s3 = csr_src[i + 3];
        float4 z0 = *(const float4*)(z + (size_t)s0 * C3 + f4);
        float4 z1 = *(const float4*)(z + (size_t)s1 * C3 + f4);
        float4 z2 = *(const float4*)(z + (size_t)s2 * C3 + f4);
        float4 z3v = *(const float4*)(z + (size_t)s3 * C3 + f4);
        acc.x += z0.x + z1.x + z2.x + z3v.x;
        acc.y += z0.y + z1.y + z2.y + z3v.y;
        acc.z += z0.z + z1.z + z2.z + z3v.z;
        acc.w += z0.w + z1.w + z2.w + z3v.w;
    }
    for (; i < hi; ++i) {
        int s = csr_src[i];
        float4 zv = *(const float4*)(z + (size_t)s * C3 + f4);
        acc.x += zv.x; acc.y += zv.y; acc.z += zv.z; acc.w += zv.w;
    }
    float nd = norm_dst[v];
    float4 bv = *(const float4*)(b3 + f4);
    float4 o;
    o.x = acc.x * nd + bv.x; o.y = acc.y * nd + bv.y;
    o.z = acc.z * nd + bv.z; o.w = acc.w * nd + bv.w;
    *(float4*)(out + (size_t)v * C3 + f4) = o;
}

// ---- bf16 MFMA GEMM, layers 1&2: 128x128 tile, BK=64, 8 waves, dbuf -------
// Cb[m][n] = bf16( rs2[m] * relu( rs1[m]*(A@Bt^T)[m,n] + bias[n] ) )
// R14: 16 K-steps of 64 (vs 32 of 32): halves barrier/drain count, same
// staged bytes. Per wave per step: 16 MFMA, 12 ds_read_b128, 4 gl_lds.
// LDS 64KB dbuf -> 2 blocks/CU. Rows are 128B in LDS: source col is
// pre-swizzled slot=(lane&7)^(row&7) with LINEAR gl_lds dest (G21);
// ds_read uses slot=(ks*4+q)^(m&7); ks=1 fragment is at +/-32 shorts
// (slot^4), sign = per-lane constant (lr&4). Grid 640 x 512 thr;
// XCD A-reuse: xcd=bid&7 owns m-tiles [xcd*10,xcd*10+10).
__global__ __launch_bounds__(512) void k_gemm_bf16(
        const unsigned short* __restrict__ A,
        const unsigned short* __restrict__ Bt,
        const float* __restrict__ bias,
        const float* __restrict__ rs1,   // norm_dst (pre-bias)
        const float* __restrict__ rs2,   // norm_src (post-relu)
        unsigned short* __restrict__ Cb) {
    __shared__ short As[2][128 * 64];
    __shared__ short Bs[2][128 * 64];
    const int t = threadIdx.x, lane = t & 63, wid = t >> 6;   // 8 waves
    const int j = blockIdx.x >> 3;
    const int m0 = ((blockIdx.x & 7) * 10 + (j >> 3)) * 128;  // XCD-grouped
    const int n0 = (j & 7) * 128;
    const int wm0 = (wid & 1) * 64, wn0 = (wid >> 1) * 32;
    const int lr = lane & 15, q = lane >> 4;

    // staging: wave wid stages rows [wid*16, wid*16+16) of A and of B.
    // Each gl_lds16 covers 8 rows (8 lanes/row x 16B). rS and rS+8 share
    // the same (row&7) swizzle.
    const int rS = wid * 16 + (lane >> 3);
    const int sS = (((lane & 7) ^ (rS & 7)) * 8);   // pre-swizzled col (elems)
    const unsigned short* aSrc = A  + (size_t)(m0 + rS) * F + sS;
    const unsigned short* bSrc = Bt + (size_t)(n0 + rS) * F + sS;
    short* aDst = &As[0][wid * 1024];               // 16 rows * 64 shorts
    short* bDst = &Bs[0][wid * 1024];

    // ds_read fragment base pointers (ks=0); ks=1 at +/-32 shorts (slot^4)
    const int dk = (lr & 4) ? -32 : 32;
    const short* ap[4];
    const short* bp[2];
#pragma unroll
    for (int mb = 0; mb < 4; ++mb) {
        int m = wm0 + mb * 16 + lr;
        ap[mb] = &As[0][m * 64 + ((q ^ (m & 7)) * 8)];
    }
#pragma unroll
    for (int nb = 0; nb < 2; ++nb) {
        int n = wn0 + nb * 16 + lr;
        bp[nb] = &Bs[0][n * 64 + ((q ^ (n & 7)) * 8)];
    }

    floatx4 acc[4][2] = {};

    // prologue: stage tile 0 into buffer 0
    gl_lds16(aSrc,         aDst);
    gl_lds16(aSrc + 8 * F, aDst + 512);
    gl_lds16(bSrc,         bDst);
    gl_lds16(bSrc + 8 * F, bDst + 512);

    for (int kt = 0; kt < F / 64; ++kt) {          // 16 K-steps
        const int buf = kt & 1;
        __syncthreads();                           // drains buf's loads
        if (kt + 1 < F / 64) {                     // prefetch next tile
            int k0 = (kt + 1) * 64;
            int bb = (buf ^ 1) * (128 * 64);
            gl_lds16(aSrc + k0,         aDst + bb);
            gl_lds16(aSrc + 8 * F + k0, aDst + bb + 512);
            gl_lds16(bSrc + k0,         bDst + bb);
            gl_lds16(bSrc + 8 * F + k0, bDst + bb + 512);
        }
        const int bo = buf * (128 * 64);
        short8 af0[4], af1[4], bf0[2], bf1[2];
#pragma unroll
        for (int mb = 0; mb < 4; ++mb) {
            af0[mb] = *(const short8*)(ap[mb] + bo);
            af1[mb] = *(const short8*)(ap[mb] + bo + dk);
        }
#pragma unroll
        for (int nb = 0; nb < 2; ++nb) {
            bf0[nb] = *(const short8*)(bp[nb] + bo);
            bf1[nb] = *(const short8*)(bp[nb] + bo + dk);
        }
#pragma unroll
        for (int mb = 0; mb < 4; ++mb)
#pragma unroll
            for (int nb = 0; nb < 2; ++nb)
                acc[mb][nb] = __builtin_amdgcn_mfma_f32_16x16x32_bf16(
                    af0[mb], bf0[nb], acc[mb][nb], 0, 0, 0);
#pragma unroll
        for (int mb = 0; mb < 4; ++mb)
#pragma unroll
            for (int nb = 0; nb < 2; ++nb)
                acc[mb][nb] = __builtin_amdgcn_mfma_f32_16x16x32_bf16(
                    af1[mb], bf1[nb], acc[mb][nb], 0, 0, 0);
    }

    float s1[4][4], s2[4][4];
#pragma unroll
    for (int mb = 0; mb < 4; ++mb)
#pragma unroll
        for (int r = 0; r < 4; ++r) {
            int row = m0 + wm0 + mb * 16 + q * 4 + r;
            s1[mb][r] = rs1[row];
            s2[mb][r] = rs2[row];
        }
#pragma unroll
    for (int nb = 0; nb < 2; ++nb) {
        int col = n0 + wn0 + nb * 16 + lr;
        float bv = bias[col];
#pragma unroll
        for (int mb = 0; mb < 4; ++mb)
#pragma unroll
            for (int r = 0; r < 4; ++r) {
                int row = m0 + wm0 + mb * 16 + q * 4 + r;
                float v = fmaxf(acc[mb][nb][r] * s1[mb][r] + bv, 0.f) * s2[mb][r];
                Cb[(size_t)row * F + col] = f2bf(v);
            }
    }
}

// ---- bf16 MFMA GEMM, layer 3: z3 = x2' @ Wt3^T, fp32 out, N=64, dbuf ------
__global__ __launch_bounds__(256) void k_gemm3(
        const unsigned short* __restrict__ A,
        const unsigned short* __restrict__ Bt,   // [64 n][F k]
        float* __restrict__ Z) {
    __shared__ short As3[2][64 * 32];
    __shared__ short Bs3[2][64 * 32];
    const int t = threadIdx.x, lane = t & 63, wid = t >> 6;
    const int m0 = blockIdx.x * 64;
    const int lr = lane & 15, q = lane >> 4;

    const int r = wid * 16 + (lane >> 2);
    const int soff = (((lane & 3) ^ ((r >> 1) & 3)) * 8);
    const unsigned short* aSrc = A  + (size_t)(m0 + r) * F + soff;
    const unsigned short* bSrc = Bt + (size_t)r * F + soff;

    const short* ap;
    {
        int m = wid * 16 + lr;
        ap = &As3[0][m * 32 + (q ^ ((m >> 1) & 3)) * 8];
    }
    const short* bp[4];
#pragma unroll
    for (int nb = 0; nb < 4; ++nb) {
        int n = nb * 16 + lr;
        bp[nb] = &Bs3[0][n * 32 + (q ^ ((n >> 1) & 3)) * 8];
    }

    floatx4 acc[4] = {};

    gl_lds16(aSrc, &As3[0][wid * 512]);
    gl_lds16(bSrc, &Bs3[0][wid * 512]);

    for (int kt = 0; kt < F / 32; ++kt) {
        const int buf = kt & 1;
        __syncthreads();
        if (kt + 1 < F / 32) {
            int k0 = (kt + 1) * 32;
            gl_lds16(aSrc + k0, &As3[buf ^ 1][wid * 512]);
            gl_lds16(bSrc + k0, &Bs3[buf ^ 1][wid * 512]);
        }
        const int bo = buf * (64 * 32);
        short8 af = *(const short8*)(ap + bo);
        short8 bf[4];
#pragma unroll
        for (int nb = 0; nb < 4; ++nb) bf[nb] = *(const short8*)(bp[nb] + bo);
#pragma unroll
        for (int nb = 0; nb < 4; ++nb)
            acc[nb] = __builtin_amdgcn_mfma_f32_16x16x32_bf16(af, bf[nb], acc[nb], 0, 0, 0);
    }

#pragma unroll
    for (int nb = 0; nb < 4; ++nb) {
        int col = nb * 16 + lr;
#pragma unroll
        for (int ri = 0; ri < 4; ++ri) {
            int row = m0 + wid * 16 + q * 4 + ri;
            Z[(size_t)row * C3 + col] = acc[nb][ri];
        }
    }
}

// ---- driver ---------------------------------------------------------------

extern "C" void kernel_launch(void* const* d_in, const int* in_sizes, int n_in,
                              void* d_out, int out_size, void* d_ws, size_t ws_size,
                              hipStream_t stream) {
    const float* h   = (const float*)d_in[0];
    const int*   src = (const int*)d_in[1];
    const int*   dst = (const int*)d_in[2];
    const float* W1  = (const float*)d_in[3];
    const float* b1  = (const float*)d_in[4];
    const float* W2  = (const float*)d_in[5];
    const float* b2  = (const float*)d_in[6];
    const float* W3  = (const float*)d_in[7];
    const float* b3  = (const float*)d_in[8];
    float* out = (float*)d_out;

    char* ws = (char*)d_ws;
    int*   deg_out  = (int*)ws;                       ws += MPAD * 4;
    int*   deg_in   = (int*)ws;                       ws += MPAD * 4;
    float* norm_src = (float*)ws;                     ws += MPAD * 4;
    float* norm_dst = (float*)ws;                     ws += MPAD * 4;
    int*   row_ptr  = (int*)ws;                       ws += (NN + 1) * 4;
    int*   cursor   = (int*)ws;                       ws += NN * 4;
    int*   csr_src  = (int*)ws;                       ws += NE * 4;
    ws = (char*)(((size_t)ws + 255) & ~(size_t)255);
    unsigned short* hb   = (unsigned short*)ws;       ws += (size_t)MPAD * F * 2;
    unsigned short* aggb = (unsigned short*)ws;       ws += (size_t)MPAD * F * 2;
    unsigned short* xb   = (unsigned short*)ws;       ws += (size_t)MPAD * F * 2;
    unsigned short* Wt1  = (unsigned short*)ws;       ws += (size_t)F * F * 2;
    unsigned short* Wt2  = (unsigned short*)ws;       ws += (size_t)F * F * 2;
    unsigned short* Wt3  = (unsigned short*)ws;       ws += (size_t)C3 * F * 2;
    float* z3       = (float*)ws;                     // MPAD * C3 * 4

    // CSR build + norms + weight conversion + h conversion
    hipMemsetAsync(deg_out, 0, 2 * MPAD * sizeof(int), stream);
    k_degree<<<(NE + 255) / 256, 256, 0, stream>>>(src, dst, deg_out, deg_in);
    k_scan<<<1, 1024, 0, stream>>>(deg_in, deg_out, row_ptr, cursor, norm_src, norm_dst);
    k_bucket<<<(NE + 255) / 256, 256, 0, stream>>>(src, dst, cursor, csr_src);
    k_wconv_all<<<2112, 256, 0, stream>>>(W1, W2, W3, Wt1, Wt2, Wt3);
    k_hcvt<<<NN * 128 / 256, 256, 0, stream>>>(h, norm_src, hb);

    // layer 1: aggb = Sum hb[src]; xb = bf16(ns.*relu(nd.*(aggb@W1)+b1))
    k_aggb<<<(NN / 16) * 8, 256, 0, stream>>>(hb, row_ptr, csr_src, aggb);
    k_gemm_bf16<<<(MPAD / 128) * (F / 128), 512, 0, stream>>>(aggb, Wt1, b1, norm_dst, norm_src, xb);

    // layer 2
    k_aggb<<<(NN / 16) * 8, 256, 0, stream>>>(xb, row_ptr, csr_src, aggb);
    k_gemm_bf16<<<(MPAD / 128) * (F / 128), 512, 0, stream>>>(aggb, Wt2, b2, norm_dst, norm_src, xb);

    // layer 3: z3 = xb @ W3t ; out = nd.*(A z3) + b3
    k_gemm3<<<MPAD / 64, 256, 0, stream>>>(xb, Wt3, z3);
    k_agg64<<<(NN + 15) / 16, 256, 0, stream>>>(z3, row_ptr, csr_src, norm_dst, b3, out);
}

// Round 8
// 291.289 us; speedup vs baseline: 1.1144x; 1.1144x over previous
//
#include <hip/hip_runtime.h>

// GCN: 3 x (gather-aggregate via CSR -> GEMM(+bias,+relu))
// R1: CSR gather aggregation (no fp32 atomics).
// R2: layers 1&2 GEMM -> bf16 MFMA, global_load_lds(16) staging, XOR swizzle.
// R3: bf16 end-to-end; layer-3 GEMM -> bf16 MFMA; fused epilogues.
// R4: double-buffered LDS in MFMA GEMMs; XCD-partitioned gather. (GEMM 43us)
// R5: XCD grid swizzle -> REGRESSED. R6: BN=64+vmcnt(3) -> REGRESSED.
// R7: 128x128 tile, 512-thread blocks (8 waves): GEMM ~38us. Kept.
// R8: k_aggb unroll x4; fuse 3x k_wconv; fold k_norm into k_scan.
// R9: k_aggb unroll x8; GEMM XCD A-reuse grouping; k_agg64 unroll x4.
//     296.8 -> 277.7 us. BEST so far.
// R10: GEMM 128x256 tile -> REGRESSED (1.25 blk/CU, occupancy cliff).
// R11: aggb half-split isolated ~-6us -> reverted.
// R12: counted-vmcnt triple-buffer -> REGRESSED (pinned waitcnt defeats
//      compiler sched in 2-phase loops; guide m131/m141).
// R13: 4-wave blocks -> REGRESSED (halves waves/CU; TLP hides the stall).
// R14: BK=64 -> REGRESSED (53-57us; 64KB LDS -> 2 blk/CU occupancy loss
//      dominates barrier-count halving). GEMM axis sweep complete: R9
//      config is the local optimum. GEMM frozen at R9.
// R16: attack k_aggb (est ~40us each, latency-bound at ~8 TB/s plateau,
//      L2-BW floor ~10us): CSR rows padded to multiples of 8 with
//      zero-row sentinel (index MPAD; hb/xb/z3 row MPAD zeroed) ->
//      tail-free unroll-8 loop + int4x2 index loads (32B-aligned starts).
//      Removes avg ~3.5 serial tail round-trips per node (+22% dummy
//      gathers, all L1-hit zero row).
constexpr int NN   = 10000;
constexpr int NE   = 160000;
constexpr int F    = 1024;
constexpr int C3   = 64;
constexpr int MPAD = 10240;   // 80 * 128; also the zero-row sentinel index
constexpr int CSRCAP = NE + NN * 8;   // 240000: worst-case padded edges

typedef __attribute__((ext_vector_type(8))) short short8;
typedef __attribute__((ext_vector_type(8))) unsigned short ushort8v;
typedef __attribute__((ext_vector_type(4))) float floatx4;

__device__ __forceinline__ unsigned short f2bf(float f) {
    union { float f; unsigned u; } v; v.f = f;
    unsigned r = v.u + 0x7fff + ((v.u >> 16) & 1);   // RNE
    return (unsigned short)(r >> 16);
}
__device__ __forceinline__ float bf2f(unsigned short u) {
    union { unsigned u; float f; } v; v.u = ((unsigned)u) << 16;
    return v.f;
}

__device__ __forceinline__ void gl_lds16(const void* g, void* l) {
    __builtin_amdgcn_global_load_lds(
        (const __attribute__((address_space(1))) unsigned int*)g,
        (__attribute__((address_space(3))) unsigned int*)l, 16, 0, 0);
}

// ---- CSR build ------------------------------------------------------------

__global__ __launch_bounds__(256) void k_degree(const int* __restrict__ src,
                                                const int* __restrict__ dst,
                                                int* __restrict__ deg_out,
                                                int* __restrict__ deg_in) {
    int e = blockIdx.x * 256 + threadIdx.x;
    if (e < NE) {
        atomicAdd(&deg_out[src[e]], 1);
        atomicAdd(&deg_in[dst[e]], 1);
    }
}

// single-block: exclusive scan of PADDED degrees (pad8) -> row_ptr/cursor,
// both norms (from real degrees), and sentinel-fill of csr_src.
__global__ __launch_bounds__(1024) void k_scan(const int* __restrict__ deg_in,
                                               const int* __restrict__ deg_out,
                                               int* __restrict__ row_ptr,
                                               int* __restrict__ cursor,
                                               float* __restrict__ norm_src,
                                               float* __restrict__ norm_dst,
                                               int* __restrict__ csr_src) {
    constexpr int CH = 10;
    __shared__ int sums[1024];
    const int tid = threadIdx.x;
    // sentinel-fill the whole padded CSR buffer (bucket overwrites real edges)
    for (int i = tid; i < CSRCAP; i += 1024) csr_src[i] = MPAD;
    int local[CH];
    int tsum = 0;
#pragma unroll
    for (int j = 0; j < CH; ++j) {
        int idx = tid * CH + j;
        int d = (idx < NN) ? deg_in[idx] : 0;
        int pd = (idx < NN) ? ((d + 7) & ~7) : 0;   // padded degree
        local[j] = pd;
        tsum += pd;
        if (idx < MPAD) {   // fused norm computation (real degrees)
            norm_src[idx] = rsqrtf(fmaxf((float)deg_out[idx], 1.0f));
            norm_dst[idx] = rsqrtf(fmaxf((float)d, 1.0f));
        }
    }
    sums[tid] = tsum;
    __syncthreads();
    for (int off = 1; off < 1024; off <<= 1) {
        int v = (tid >= off) ? sums[tid - off] : 0;
        __syncthreads();
        sums[tid] += v;
        __syncthreads();
    }
    int run = sums[tid] - tsum;
#pragma unroll
    for (int j = 0; j < CH; ++j) {
        int idx = tid * CH + j;
        if (idx < NN) {
            row_ptr[idx] = run;
            cursor[idx]  = run;
        }
        run += local[j];
    }
    if (tid == 1023) row_ptr[NN] = sums[1023];
}

__global__ __launch_bounds__(256) void k_bucket(const int* __restrict__ src,
                                                const int* __restrict__ dst,
                                                int* __restrict__ cursor,
                                                int* __restrict__ csr_src) {
    int e = blockIdx.x * 256 + threadIdx.x;
    if (e < NE) {
        int slot = atomicAdd(&cursor[dst[e]], 1);
        csr_src[slot] = src[e];
    }
}

// ---- fused weight transpose+convert: all three W -> Wt bf16 [n][k=F] ------
// blocks 0..1023: W1; 1024..2047: W2; 2048..2111: W3 (N=C3).
__global__ __launch_bounds__(256) void k_wconv_all(const float* __restrict__ W1,
                                                   const float* __restrict__ W2,
                                                   const float* __restrict__ W3,
                                                   unsigned short* __restrict__ Wt1,
                                                   unsigned short* __restrict__ Wt2,
                                                   unsigned short* __restrict__ Wt3) {
    __shared__ float tile[32][33];
    const float* W; unsigned short* Wt; int N, n0, k0;
    int b = blockIdx.x;
    if (b < 1024)      { W = W1; Wt = Wt1; N = F;  n0 = (b & 31) * 32;          k0 = (b >> 5) * 32; }
    else if (b < 2048) { b -= 1024; W = W2; Wt = Wt2; N = F;  n0 = (b & 31) * 32; k0 = (b >> 5) * 32; }
    else               { b -= 2048; W = W3; Wt = Wt3; N = C3; n0 = (b & 1) * 32;  k0 = (b >> 1) * 32; }
    const int tx = threadIdx.x & 31, ty = threadIdx.x >> 5;   // 32 x 8
#pragma unroll
    for (int i = 0; i < 32; i += 8)
        tile[ty + i][tx] = W[(size_t)(k0 + ty + i) * N + n0 + tx];  // [k][n]
    __syncthreads();
#pragma unroll
    for (int i = 0; i < 32; i += 8)
        Wt[(size_t)(n0 + ty + i) * F + k0 + tx] = f2bf(tile[tx][ty + i]);
}

// ---- h -> bf16 with norm_src fold, plus zero rows [NN, MPAD] of hb AND xb -
// (row MPAD is the gather sentinel's zero row; rows NN..MPAD-1 of xb get
// overwritten by the GEMM later -- only row MPAD must survive, and it does.)

__global__ __launch_bounds__(256) void k_hcvt(const float* __restrict__ h,
                                              const float* __restrict__ norm_src,
                                              unsigned short* __restrict__ hb,
                                              unsigned short* __restrict__ xb) {
    int idx = blockIdx.x * 256 + threadIdx.x;     // (MPAD+1)*128 total
    if (idx >= (MPAD + 1) * 128) return;
    int v = idx >> 7, f8 = (idx & 127) * 8;
    if (v >= NN) {
        ushort8v z = {0, 0, 0, 0, 0, 0, 0, 0};
        *(ushort8v*)(hb + (size_t)v * F + f8) = z;
        *(ushort8v*)(xb + (size_t)v * F + f8) = z;
        return;
    }
    float ns = norm_src[v];
    const float4 a = *(const float4*)(h + (size_t)v * F + f8);
    const float4 b = *(const float4*)(h + (size_t)v * F + f8 + 4);
    ushort8v o;
    o[0] = f2bf(ns * a.x); o[1] = f2bf(ns * a.y);
    o[2] = f2bf(ns * a.z); o[3] = f2bf(ns * a.w);
    o[4] = f2bf(ns * b.x); o[5] = f2bf(ns * b.y);
    o[6] = f2bf(ns * b.z); o[7] = f2bf(ns * b.w);
    *(ushort8v*)(hb + (size_t)v * F + f8) = o;
}

// ---- aggregation: bf16 in, fp32 accumulate, bf16 out ----------------------
// XCD-partitioned: chunk c = blockIdx%8 -> per-XCD slice 2.56 MB < 4 MB L2.
// 16 nodes per block, 16 lanes x 8 bf16 (16B) per node.
// R16: padded CSR (multiples of 8, sentinel=zero row) -> tail-free loop,
// int4x2 index loads (32B-aligned row starts), 8 gathers in flight.
__global__ __launch_bounds__(256) void k_aggb(const unsigned short* __restrict__ xb,
                                              const int* __restrict__ row_ptr,
                                              const int* __restrict__ csr_src,
                                              unsigned short* __restrict__ aggb) {
    const int c = blockIdx.x & 7;                       // feature chunk -> XCD
    const int g = blockIdx.x >> 3;                      // node group
    const int v = g * 16 + (threadIdx.x >> 4);          // 625*16 == NN exactly
    const int f8 = c * 128 + (threadIdx.x & 15) * 8;
    const unsigned short* xr = xb + f8;
    const int lo = row_ptr[v], hi = row_ptr[v + 1];     // hi-lo multiple of 8
    float acc[8] = {0.f, 0.f, 0.f, 0.f, 0.f, 0.f, 0.f, 0.f};
    for (int i = lo; i < hi; i += 8) {
        const int4 ia = *(const int4*)(csr_src + i);
        const int4 ib = *(const int4*)(csr_src + i + 4);
        ushort8v x0 = *(const ushort8v*)(xr + (size_t)ia.x * F);
        ushort8v x1 = *(const ushort8v*)(xr + (size_t)ia.y * F);
        ushort8v x2 = *(const ushort8v*)(xr + (size_t)ia.z * F);
        ushort8v x3 = *(const ushort8v*)(xr + (size_t)ia.w * F);
        ushort8v x4 = *(const ushort8v*)(xr + (size_t)ib.x * F);
        ushort8v x5 = *(const ushort8v*)(xr + (size_t)ib.y * F);
        ushort8v x6 = *(const ushort8v*)(xr + (size_t)ib.z * F);
        ushort8v x7 = *(const ushort8v*)(xr + (size_t)ib.w * F);
#pragma unroll
        for (int j = 0; j < 8; ++j) acc[j] += bf2f(x0[j]);
#pragma unroll
        for (int j = 0; j < 8; ++j) acc[j] += bf2f(x1[j]);
#pragma unroll
        for (int j = 0; j < 8; ++j) acc[j] += bf2f(x2[j]);
#pragma unroll
        for (int j = 0; j < 8; ++j) acc[j] += bf2f(x3[j]);
#pragma unroll
        for (int j = 0; j < 8; ++j) acc[j] += bf2f(x4[j]);
#pragma unroll
        for (int j = 0; j < 8; ++j) acc[j] += bf2f(x5[j]);
#pragma unroll
        for (int j = 0; j < 8; ++j) acc[j] += bf2f(x6[j]);
#pragma unroll
        for (int j = 0; j < 8; ++j) acc[j] += bf2f(x7[j]);
    }
    ushort8v o;
#pragma unroll
    for (int j = 0; j < 8; ++j) o[j] = f2bf(acc[j]);
    *(ushort8v*)(aggb + (size_t)v * F + f8) = o;
}

// layer-3 aggregation over z3 (fp32, 64 feats), fused nd/bias, writes d_out.
// 16 nodes per block, 16 lanes x float4 per node. Padded CSR: unroll-4
// always exact (hi-lo multiple of 8); sentinel reads z3 row MPAD = 0.
__global__ __launch_bounds__(256) void k_agg64(const float* __restrict__ z,
                                               const int* __restrict__ row_ptr,
                                               const int* __restrict__ csr_src,
                                               const float* __restrict__ norm_dst,
                                               const float* __restrict__ b3,
                                               float* __restrict__ out) {
    const int v = blockIdx.x * 16 + (threadIdx.x >> 4);
    if (v >= NN) return;
    const int f4 = (threadIdx.x & 15) * 4;
    const int lo = row_ptr[v], hi = row_ptr[v + 1];
    float4 acc = {0.f, 0.f, 0.f, 0.f};
    for (int i = lo; i + 4 <= hi; i += 4) {
        const int4 s = *(const int4*)(csr_src + i);
        float4 z0 = *(const float4*)(z + (size_t)s.x * C3 + f4);
        float4 z1 = *(const float4*)(z + (size_t)s.y * C3 + f4);
        float4 z2 = *(const float4*)(z + (size_t)s.z * C3 + f4);
        float4 z3v = *(const float4*)(z + (size_t)s.w * C3 + f4);
        acc.x += z0.x + z1.x + z2.x + z3v.x;
        acc.y += z0.y + z1.y + z2.y + z3v.y;
        acc.z += z0.z + z1.z + z2.z + z3v.z;
        acc.w += z0.w + z1.w + z2.w + z3v.w;
    }
    float nd = norm_dst[v];
    float4 bv = *(const float4*)(b3 + f4);
    float4 o;
    o.x = acc.x * nd + bv.x; o.y = acc.y * nd + bv.y;
    o.z = acc.z * nd + bv.z; o.w = acc.w * nd + bv.w;
    *(float4*)(out + (size_t)v * C3 + f4) = o;
}

// ---- bf16 MFMA GEMM, layers 1&2: 128x128 tile, 8 waves, double-buffered ---
// EXACT R9 config (proven local optimum; R10/R12/R13/R14 all regressed).
// Grid 640 x 512 thr (2.5 blk/CU); XCD A-reuse: xcd=bid&7 owns m-tiles
// [xcd*10,xcd*10+10), all 8 n-blocks of an m-tile on that XCD.
__global__ __launch_bounds__(512) void k_gemm_bf16(
        const unsigned short* __restrict__ A,
        const unsigned short* __restrict__ Bt,
        const float* __restrict__ bias,
        const float* __restrict__ rs1,   // norm_dst (pre-bias)
        const float* __restrict__ rs2,   // norm_src (post-relu)
        unsigned short* __restrict__ Cb) {
    __shared__ short As[2][128 * 32];
    __shared__ short Bs[2][128 * 32];
    const int t = threadIdx.x, lane = t & 63, wid = t >> 6;   // 8 waves
    const int j = blockIdx.x >> 3;
    const int m0 = ((blockIdx.x & 7) * 10 + (j >> 3)) * 128;  // XCD-grouped
    const int n0 = (j & 7) * 128;
    const int wm0 = (wid & 1) * 64, wn0 = (wid >> 1) * 32;
    const int lr = lane & 15, q = lane >> 4;

    // staging: wave wid -> tile-instr wid for both A and B (16 rows each)
    const int rS  = wid * 16 + (lane >> 2);
    const int sS  = (((lane & 3) ^ ((rS >> 1) & 3)) * 8);
    const unsigned short* aSrc = A  + (size_t)(m0 + rS) * F + sS;
    const unsigned short* bSrc = Bt + (size_t)(n0 + rS) * F + sS;
    short* aDst = &As[0][wid * 512];
    short* bDst = &Bs[0][wid * 512];

    // ds_read fragment base pointers (buffer 0)
    const short* ap[4];
    const short* bp[2];
#pragma unroll
    for (int mb = 0; mb < 4; ++mb) {
        int m = wm0 + mb * 16 + lr;
        ap[mb] = &As[0][m * 32 + (q ^ ((m >> 1) & 3)) * 8];
    }
#pragma unroll
    for (int nb = 0; nb < 2; ++nb) {
        int n = wn0 + nb * 16 + lr;
        bp[nb] = &Bs[0][n * 32 + (q ^ ((n >> 1) & 3)) * 8];
    }

    floatx4 acc[4][2] = {};

    // prologue: stage tile 0 into buffer 0
    gl_lds16(aSrc, aDst);
    gl_lds16(bSrc, bDst);

    for (int kt = 0; kt < F / 32; ++kt) {
        const int buf = kt & 1;
        __syncthreads();                       // drains buf's loads (issued kt-1)
        if (kt + 1 < F / 32) {                 // prefetch next tile into other buf
            int k0 = (kt + 1) * 32;
            gl_lds16(aSrc + k0, aDst + (buf ^ 1) * (128 * 32));
            gl_lds16(bSrc + k0, bDst + (buf ^ 1) * (128 * 32));
        }
        const int bo = buf * (128 * 32);
        short8 af[4], bf[2];
#pragma unroll
        for (int mb = 0; mb < 4; ++mb) af[mb] = *(const short8*)(ap[mb] + bo);
#pragma unroll
        for (int nb = 0; nb < 2; ++nb) bf[nb] = *(const short8*)(bp[nb] + bo);
#pragma unroll
        for (int mb = 0; mb < 4; ++mb)
#pragma unroll
            for (int nb = 0; nb < 2; ++nb)
                acc[mb][nb] = __builtin_amdgcn_mfma_f32_16x16x32_bf16(
                    af[mb], bf[nb], acc[mb][nb], 0, 0, 0);
    }

    float s1[4][4], s2[4][4];
#pragma unroll
    for (int mb = 0; mb < 4; ++mb)
#pragma unroll
        for (int r = 0; r < 4; ++r) {
            int row = m0 + wm0 + mb * 16 + q * 4 + r;
            s1[mb][r] = rs1[row];
            s2[mb][r] = rs2[row];
        }
#pragma unroll
    for (int nb = 0; nb < 2; ++nb) {
        int col = n0 + wn0 + nb * 16 + lr;
        float bv = bias[col];
#pragma unroll
        for (int mb = 0; mb < 4; ++mb)
#pragma unroll
            for (int r = 0; r < 4; ++r) {
                int row = m0 + wm0 + mb * 16 + q * 4 + r;
                float v = fmaxf(acc[mb][nb][r] * s1[mb][r] + bv, 0.f) * s2[mb][r];
                Cb[(size_t)row * F + col] = f2bf(v);
            }
    }
}

// ---- bf16 MFMA GEMM, layer 3: z3 = x2' @ Wt3^T, fp32 out, N=64, dbuf ------
__global__ __launch_bounds__(256) void k_gemm3(
        const unsigned short* __restrict__ A,
        const unsigned short* __restrict__ Bt,   // [64 n][F k]
        float* __restrict__ Z) {
    __shared__ short As3[2][64 * 32];
    __shared__ short Bs3[2][64 * 32];
    const int t = threadIdx.x, lane = t & 63, wid = t >> 6;
    const int m0 = blockIdx.x * 64;
    const int lr = lane & 15, q = lane >> 4;

    const int r = wid * 16 + (lane >> 2);
    const int soff = (((lane & 3) ^ ((r >> 1) & 3)) * 8);
    const unsigned short* aSrc = A  + (size_t)(m0 + r) * F + soff;
    const unsigned short* bSrc = Bt + (size_t)r * F + soff;

    const short* ap;
    {
        int m = wid * 16 + lr;
        ap = &As3[0][m * 32 + (q ^ ((m >> 1) & 3)) * 8];
    }
    const short* bp[4];
#pragma unroll
    for (int nb = 0; nb < 4; ++nb) {
        int n = nb * 16 + lr;
        bp[nb] = &Bs3[0][n * 32 + (q ^ ((n >> 1) & 3)) * 8];
    }

    floatx4 acc[4] = {};

    gl_lds16(aSrc, &As3[0][wid * 512]);
    gl_lds16(bSrc, &Bs3[0][wid * 512]);

    for (int kt = 0; kt < F / 32; ++kt) {
        const int buf = kt & 1;
        __syncthreads();
        if (kt + 1 < F / 32) {
            int k0 = (kt + 1) * 32;
            gl_lds16(aSrc + k0, &As3[buf ^ 1][wid * 512]);
            gl_lds16(bSrc + k0, &Bs3[buf ^ 1][wid * 512]);
        }
        const int bo = buf * (64 * 32);
        short8 af = *(const short8*)(ap + bo);
        short8 bf[4];
#pragma unroll
        for (int nb = 0; nb < 4; ++nb) bf[nb] = *(const short8*)(bp[nb] + bo);
#pragma unroll
        for (int nb = 0; nb < 4; ++nb)
            acc[nb] = __builtin_amdgcn_mfma_f32_16x16x32_bf16(af, bf[nb], acc[nb], 0, 0, 0);
    }

#pragma unroll
    for (int nb = 0; nb < 4; ++nb) {
        int col = nb * 16 + lr;
#pragma unroll
        for (int ri = 0; ri < 4; ++ri) {
            int row = m0 + wid * 16 + q * 4 + ri;
            Z[(size_t)row * C3 + col] = acc[nb][ri];
        }
    }
}

// ---- driver ---------------------------------------------------------------

extern "C" void kernel_launch(void* const* d_in, const int* in_sizes, int n_in,
                              void* d_out, int out_size, void* d_ws, size_t ws_size,
                              hipStream_t stream) {
    const float* h   = (const float*)d_in[0];
    const int*   src = (const int*)d_in[1];
    const int*   dst = (const int*)d_in[2];
    const float* W1  = (const float*)d_in[3];
    const float* b1  = (const float*)d_in[4];
    const float* W2  = (const float*)d_in[5];
    const float* b2  = (const float*)d_in[6];
    const float* W3  = (const float*)d_in[7];
    const float* b3  = (const float*)d_in[8];
    float* out = (float*)d_out;

    char* ws = (char*)d_ws;
    int*   deg_out  = (int*)ws;                       ws += MPAD * 4;
    int*   deg_in   = (int*)ws;                       ws += MPAD * 4;
    float* norm_src = (float*)ws;                     ws += MPAD * 4;
    float* norm_dst = (float*)ws;                     ws += MPAD * 4;
    int*   row_ptr  = (int*)ws;                       ws += (NN + 1) * 4;
    int*   cursor   = (int*)ws;                       ws += NN * 4;
    int*   csr_src  = (int*)ws;                       ws += CSRCAP * 4;
    ws = (char*)(((size_t)ws + 255) & ~(size_t)255);
    unsigned short* hb   = (unsigned short*)ws;       ws += (size_t)(MPAD + 1) * F * 2;
    unsigned short* aggb = (unsigned short*)ws;       ws += (size_t)MPAD * F * 2;
    unsigned short* xb   = (unsigned short*)ws;       ws += (size_t)(MPAD + 1) * F * 2;
    unsigned short* Wt1  = (unsigned short*)ws;       ws += (size_t)F * F * 2;
    unsigned short* Wt2  = (unsigned short*)ws;       ws += (size_t)F * F * 2;
    unsigned short* Wt3  = (unsigned short*)ws;       ws += (size_t)C3 * F * 2;
    float* z3       = (float*)ws;                     // (MPAD+1) * C3 * 4

    // CSR build + norms + weight conversion + h conversion
    hipMemsetAsync(deg_out, 0, 2 * MPAD * sizeof(int), stream);
    hipMemsetAsync(z3 + (size_t)MPAD * C3, 0, C3 * sizeof(float), stream);  // ZR row
    k_degree<<<(NE + 255) / 256, 256, 0, stream>>>(src, dst, deg_out, deg_in);
    k_scan<<<1, 1024, 0, stream>>>(deg_in, deg_out, row_ptr, cursor, norm_src, norm_dst, csr_src);
    k_bucket<<<(NE + 255) / 256, 256, 0, stream>>>(src, dst, cursor, csr_src);
    k_wconv_all<<<2112, 256, 0, stream>>>(W1, W2, W3, Wt1, Wt2, Wt3);
    k_hcvt<<<((MPAD + 1) * 128 + 255) / 256, 256, 0, stream>>>(h, norm_src, hb, xb);

    // layer 1: aggb = Sum hb[src]; xb = bf16(ns.*relu(nd.*(aggb@W1)+b1))
    k_aggb<<<(NN / 16) * 8, 256, 0, stream>>>(hb, row_ptr, csr_src, aggb);
    k_gemm_bf16<<<(MPAD / 128) * (F / 128), 512, 0, stream>>>(aggb, Wt1, b1, norm_dst, norm_src, xb);

    // layer 2
    k_aggb<<<(NN / 16) * 8, 256, 0, stream>>>(xb, row_ptr, csr_src, aggb);
    k_gemm_bf16<<<(MPAD / 128) * (F / 128), 512, 0, stream>>>(aggb, Wt2, b2, norm_dst, norm_src, xb);

    // layer 3: z3 = xb @ W3t ; out = nd.*(A z3) + b3
    k_gemm3<<<MPAD / 64, 256, 0, stream>>>(xb, Wt3, z3);
    k_agg64<<<(NN + 15) / 16, 256, 0, stream>>>(z3, row_ptr, csr_src, norm_dst, b3, out);
}

// Round 9
// 277.095 us; speedup vs baseline: 1.1715x; 1.0512x over previous
//
#include <hip/hip_runtime.h>

// GCN: 3 x (gather-aggregate via CSR -> GEMM(+bias,+relu))
// R1: CSR gather aggregation (no fp32 atomics).
// R2: layers 1&2 GEMM -> bf16 MFMA, global_load_lds(16) staging, XOR swizzle.
// R3: bf16 end-to-end; layer-3 GEMM -> bf16 MFMA; fused epilogues.
// R4: double-buffered LDS in MFMA GEMMs; XCD-partitioned gather. (GEMM 43us)
// R5: XCD grid swizzle -> REGRESSED. R6: BN=64+vmcnt(3) -> REGRESSED.
// R7: 128x128 tile, 512-thread blocks (8 waves): GEMM ~38us. Kept.
// R8: k_aggb unroll x4; fuse 3x k_wconv; fold k_norm into k_scan.
// R9: k_aggb unroll x8; GEMM XCD A-reuse grouping; k_agg64 unroll x4.
//     296.8 -> 277.7 us. BEST.
// R10: GEMM 128x256 tile -> REGRESSED (1.25 blk/CU occupancy cliff).
// R11: aggb half-split isolated ~-6us -> reverted.
// R12: counted-vmcnt triple-buffer -> REGRESSED (guide m131/m141).
// R13: 4-wave blocks -> REGRESSED (halves waves/CU TLP).
// R14: BK=64 -> REGRESSED (64KB LDS occupancy loss dominates).
// R16: CSR pad8 + sentinel -> REGRESSED (291.3): aggb is gather-COUNT
//      bound (~8 TB/s plateau); +25% dummy gathers cost ~20us, tail
//      removal refunded ~6. aggb floor = ~40us/layer (327MB mandatory).
// R17: exact R9 revert + merge {bucket, wconv, hcvt} into one dispatch
//      (all depend only on k_scan; block-range split). 12 -> 10 launches,
//      three small-kernel tails overlap. Hot kernels untouched.
constexpr int NN   = 10000;
constexpr int NE   = 160000;
constexpr int F    = 1024;
constexpr int C3   = 64;
constexpr int MPAD = 10240;   // 80 * 128

typedef __attribute__((ext_vector_type(8))) short short8;
typedef __attribute__((ext_vector_type(8))) unsigned short ushort8v;
typedef __attribute__((ext_vector_type(4))) float floatx4;

__device__ __forceinline__ unsigned short f2bf(float f) {
    union { float f; unsigned u; } v; v.f = f;
    unsigned r = v.u + 0x7fff + ((v.u >> 16) & 1);   // RNE
    return (unsigned short)(r >> 16);
}
__device__ __forceinline__ float bf2f(unsigned short u) {
    union { unsigned u; float f; } v; v.u = ((unsigned)u) << 16;
    return v.f;
}

__device__ __forceinline__ void gl_lds16(const void* g, void* l) {
    __builtin_amdgcn_global_load_lds(
        (const __attribute__((address_space(1))) unsigned int*)g,
        (__attribute__((address_space(3))) unsigned int*)l, 16, 0, 0);
}

// ---- CSR build ------------------------------------------------------------

__global__ __launch_bounds__(256) void k_degree(const int* __restrict__ src,
                                                const int* __restrict__ dst,
                                                int* __restrict__ deg_out,
                                                int* __restrict__ deg_in) {
    int e = blockIdx.x * 256 + threadIdx.x;
    if (e < NE) {
        atomicAdd(&deg_out[src[e]], 1);
        atomicAdd(&deg_in[dst[e]], 1);
    }
}

// single-block: exclusive scan of deg_in -> row_ptr/cursor, plus both norms
// (1024 threads x CH=10 covers 10240 == MPAD).
__global__ __launch_bounds__(1024) void k_scan(const int* __restrict__ deg_in,
                                               const int* __restrict__ deg_out,
                                               int* __restrict__ row_ptr,
                                               int* __restrict__ cursor,
                                               float* __restrict__ norm_src,
                                               float* __restrict__ norm_dst) {
    constexpr int CH = 10;
    __shared__ int sums[1024];
    const int tid = threadIdx.x;
    int local[CH];
    int tsum = 0;
#pragma unroll
    for (int j = 0; j < CH; ++j) {
        int idx = tid * CH + j;
        int v = (idx < NN) ? deg_in[idx] : 0;
        local[j] = v;
        tsum += v;
        if (idx < MPAD) {   // fused norm computation (padded rows: deg=0 -> 1.0)
            norm_src[idx] = rsqrtf(fmaxf((float)deg_out[idx], 1.0f));
            norm_dst[idx] = rsqrtf(fmaxf((float)deg_in[idx], 1.0f));
        }
    }
    sums[tid] = tsum;
    __syncthreads();
    for (int off = 1; off < 1024; off <<= 1) {
        int v = (tid >= off) ? sums[tid - off] : 0;
        __syncthreads();
        sums[tid] += v;
        __syncthreads();
    }
    int run = sums[tid] - tsum;
#pragma unroll
    for (int j = 0; j < CH; ++j) {
        int idx = tid * CH + j;
        if (idx < NN) {
            row_ptr[idx] = run;
            cursor[idx]  = run;
        }
        run += local[j];
    }
    if (tid == 1023) row_ptr[NN] = sums[1023];
}

// ---- merged mid phase: bucket | wconv | hcvt (all depend only on k_scan) --
// blocks [0,625): bucket; [625,2737): wconv (2112); [2737,7737): hcvt (5000).
__global__ __launch_bounds__(256) void k_mid(const int* __restrict__ src,
                                             const int* __restrict__ dst,
                                             int* __restrict__ cursor,
                                             int* __restrict__ csr_src,
                                             const float* __restrict__ W1,
                                             const float* __restrict__ W2,
                                             const float* __restrict__ W3,
                                             unsigned short* __restrict__ Wt1,
                                             unsigned short* __restrict__ Wt2,
                                             unsigned short* __restrict__ Wt3,
                                             const float* __restrict__ h,
                                             const float* __restrict__ norm_src,
                                             unsigned short* __restrict__ hb) {
    __shared__ float tile[32][33];
    const int bid = blockIdx.x;
    if (bid < 625) {
        // ---- bucket: scatter edges into CSR slots
        int e = bid * 256 + threadIdx.x;
        if (e < NE) {
            int slot = atomicAdd(&cursor[dst[e]], 1);
            csr_src[slot] = src[e];
        }
        return;
    }
    if (bid < 2737) {
        // ---- weight transpose+convert -> Wt bf16 [n][k=F]
        const float* W; unsigned short* Wt; int N, n0, k0;
        int b = bid - 625;
        if (b < 1024)      { W = W1; Wt = Wt1; N = F;  n0 = (b & 31) * 32;          k0 = (b >> 5) * 32; }
        else if (b < 2048) { b -= 1024; W = W2; Wt = Wt2; N = F;  n0 = (b & 31) * 32; k0 = (b >> 5) * 32; }
        else               { b -= 2048; W = W3; Wt = Wt3; N = C3; n0 = (b & 1) * 32;  k0 = (b >> 1) * 32; }
        const int tx = threadIdx.x & 31, ty = threadIdx.x >> 5;   // 32 x 8
#pragma unroll
        for (int i = 0; i < 32; i += 8)
            tile[ty + i][tx] = W[(size_t)(k0 + ty + i) * N + n0 + tx];  // [k][n]
        __syncthreads();
#pragma unroll
        for (int i = 0; i < 32; i += 8)
            Wt[(size_t)(n0 + ty + i) * F + k0 + tx] = f2bf(tile[tx][ty + i]);
        return;
    }
    // ---- h -> bf16 with norm_src fold: hb[v][f] = bf16(ns[v]*h[v][f])
    int idx = (bid - 2737) * 256 + threadIdx.x;       // NN*128 total
    int v = idx >> 7, f8 = (idx & 127) * 8;
    float ns = norm_src[v];
    const float4 a = *(const float4*)(h + (size_t)v * F + f8);
    const float4 b = *(const float4*)(h + (size_t)v * F + f8 + 4);
    ushort8v o;
    o[0] = f2bf(ns * a.x); o[1] = f2bf(ns * a.y);
    o[2] = f2bf(ns * a.z); o[3] = f2bf(ns * a.w);
    o[4] = f2bf(ns * b.x); o[5] = f2bf(ns * b.y);
    o[6] = f2bf(ns * b.z); o[7] = f2bf(ns * b.w);
    *(ushort8v*)(hb + (size_t)v * F + f8) = o;
}

// ---- aggregation: bf16 in, fp32 accumulate, bf16 out ----------------------
// XCD-partitioned: chunk c = blockIdx%8 -> per-XCD slice 2.56 MB < 4 MB L2.
// 16 nodes per block, 16 lanes x 8 bf16 (16B) per node. Edge loop unroll x8
// (8 idx loads + 8 gathers in flight). R9 config = proven local optimum
// (R10/R11 half-split worse; R16 padding worse: time ~ gather count).
__global__ __launch_bounds__(256) void k_aggb(const unsigned short* __restrict__ xb,
                                              const int* __restrict__ row_ptr,
                                              const int* __restrict__ csr_src,
                                              unsigned short* __restrict__ aggb) {
    const int c = blockIdx.x & 7;                       // feature chunk -> XCD
    const int g = blockIdx.x >> 3;                      // node group
    const int v = g * 16 + (threadIdx.x >> 4);          // 625*16 == NN exactly
    const int f8 = c * 128 + (threadIdx.x & 15) * 8;
    const unsigned short* xr = xb + f8;
    const int lo = row_ptr[v], hi = row_ptr[v + 1];
    float acc[8] = {0.f, 0.f, 0.f, 0.f, 0.f, 0.f, 0.f, 0.f};
    int i = lo;
    for (; i + 8 <= hi; i += 8) {
        int s0 = csr_src[i],     s1 = csr_src[i + 1];
        int s2 = csr_src[i + 2], s3 = csr_src[i + 3];
        int s4 = csr_src[i + 4], s5 = csr_src[i + 5];
        int s6 = csr_src[i + 6], s7 = csr_src[i + 7];
        ushort8v x0 = *(const ushort8v*)(xr + (size_t)s0 * F);
        ushort8v x1 = *(const ushort8v*)(xr + (size_t)s1 * F);
        ushort8v x2 = *(const ushort8v*)(xr + (size_t)s2 * F);
        ushort8v x3 = *(const ushort8v*)(xr + (size_t)s3 * F);
        ushort8v x4 = *(const ushort8v*)(xr + (size_t)s4 * F);
        ushort8v x5 = *(const ushort8v*)(xr + (size_t)s5 * F);
        ushort8v x6 = *(const ushort8v*)(xr + (size_t)s6 * F);
        ushort8v x7 = *(const ushort8v*)(xr + (size_t)s7 * F);
#pragma unroll
        for (int j = 0; j < 8; ++j) acc[j] += bf2f(x0[j]);
#pragma unroll
        for (int j = 0; j < 8; ++j) acc[j] += bf2f(x1[j]);
#pragma unroll
        for (int j = 0; j < 8; ++j) acc[j] += bf2f(x2[j]);
#pragma unroll
        for (int j = 0; j < 8; ++j) acc[j] += bf2f(x3[j]);
#pragma unroll
        for (int j = 0; j < 8; ++j) acc[j] += bf2f(x4[j]);
#pragma unroll
        for (int j = 0; j < 8; ++j) acc[j] += bf2f(x5[j]);
#pragma unroll
        for (int j = 0; j < 8; ++j) acc[j] += bf2f(x6[j]);
#pragma unroll
        for (int j = 0; j < 8; ++j) acc[j] += bf2f(x7[j]);
    }
    for (; i < hi; ++i) {
        int s = csr_src[i];
        ushort8v xv = *(const ushort8v*)(xr + (size_t)s * F);
#pragma unroll
        for (int j = 0; j < 8; ++j) acc[j] += bf2f(xv[j]);
    }
    ushort8v o;
#pragma unroll
    for (int j = 0; j < 8; ++j) o[j] = f2bf(acc[j]);
    *(ushort8v*)(aggb + (size_t)v * F + f8) = o;
}

// layer-3 aggregation over z3 (fp32, 64 feats), fused nd/bias, writes d_out.
// 16 nodes per block, 16 lanes x float4 per node. R9: unroll x4.
__global__ __launch_bounds__(256) void k_agg64(const float* __restrict__ z,
                                               const int* __restrict__ row_ptr,
                                               const int* __restrict__ csr_src,
                                               const float* __restrict__ norm_dst,
                                               const float* __restrict__ b3,
                                               float* __restrict__ out) {
    const int v = blockIdx.x * 16 + (threadIdx.x >> 4);
    if (v >= NN) return;
    const int f4 = (threadIdx.x & 15) * 4;
    const int lo = row_ptr[v], hi = row_ptr[v + 1];
    float4 acc = {0.f, 0.f, 0.f, 0.f};
    int i = lo;
    for (; i + 4 <= hi; i += 4) {
        int s0 = csr_src[i],     s1 = csr_src[i + 1];
        int s2 = csr_src[i + 2], s3 = csr_src[i + 3];
        float4 z0 = *(const float4*)(z + (size_t)s0 * C3 + f4);
        float4 z1 = *(const float4*)(z + (size_t)s1 * C3 + f4);
        float4 z2 = *(const float4*)(z + (size_t)s2 * C3 + f4);
        float4 z3v = *(const float4*)(z + (size_t)s3 * C3 + f4);
        acc.x += z0.x + z1.x + z2.x + z3v.x;
        acc.y += z0.y + z1.y + z2.y + z3v.y;
        acc.z += z0.z + z1.z + z2.z + z3v.z;
        acc.w += z0.w + z1.w + z2.w + z3v.w;
    }
    for (; i < hi; ++i) {
        int s = csr_src[i];
        float4 zv = *(const float4*)(z + (size_t)s * C3 + f4);
        acc.x += zv.x; acc.y += zv.y; acc.z += zv.z; acc.w += zv.w;
    }
    float nd = norm_dst[v];
    float4 bv = *(const float4*)(b3 + f4);
    float4 o;
    o.x = acc.x * nd + bv.x; o.y = acc.y * nd + bv.y;
    o.z = acc.z * nd + bv.z; o.w = acc.w * nd + bv.w;
    *(float4*)(out + (size_t)v * C3 + f4) = o;
}

// ---- bf16 MFMA GEMM, layers 1&2: 128x128 tile, 8 waves, double-buffered ---
// EXACT R9 config (proven local optimum; R10/R12/R13/R14 all regressed).
// Grid 640 x 512 thr (2.5 blk/CU); XCD A-reuse: xcd=bid&7 owns m-tiles
// [xcd*10,xcd*10+10), all 8 n-blocks of an m-tile on that XCD.
__global__ __launch_bounds__(512) void k_gemm_bf16(
        const unsigned short* __restrict__ A,
        const unsigned short* __restrict__ Bt,
        const float* __restrict__ bias,
        const float* __restrict__ rs1,   // norm_dst (pre-bias)
        const float* __restrict__ rs2,   // norm_src (post-relu)
        unsigned short* __restrict__ Cb) {
    __shared__ short As[2][128 * 32];
    __shared__ short Bs[2][128 * 32];
    const int t = threadIdx.x, lane = t & 63, wid = t >> 6;   // 8 waves
    const int j = blockIdx.x >> 3;
    const int m0 = ((blockIdx.x & 7) * 10 + (j >> 3)) * 128;  // XCD-grouped
    const int n0 = (j & 7) * 128;
    const int wm0 = (wid & 1) * 64, wn0 = (wid >> 1) * 32;
    const int lr = lane & 15, q = lane >> 4;

    // staging: wave wid -> tile-instr wid for both A and B (16 rows each)
    const int rS  = wid * 16 + (lane >> 2);
    const int sS  = (((lane & 3) ^ ((rS >> 1) & 3)) * 8);
    const unsigned short* aSrc = A  + (size_t)(m0 + rS) * F + sS;
    const unsigned short* bSrc = Bt + (size_t)(n0 + rS) * F + sS;
    short* aDst = &As[0][wid * 512];
    short* bDst = &Bs[0][wid * 512];

    // ds_read fragment base pointers (buffer 0)
    const short* ap[4];
    const short* bp[2];
#pragma unroll
    for (int mb = 0; mb < 4; ++mb) {
        int m = wm0 + mb * 16 + lr;
        ap[mb] = &As[0][m * 32 + (q ^ ((m >> 1) & 3)) * 8];
    }
#pragma unroll
    for (int nb = 0; nb < 2; ++nb) {
        int n = wn0 + nb * 16 + lr;
        bp[nb] = &Bs[0][n * 32 + (q ^ ((n >> 1) & 3)) * 8];
    }

    floatx4 acc[4][2] = {};

    // prologue: stage tile 0 into buffer 0
    gl_lds16(aSrc, aDst);
    gl_lds16(bSrc, bDst);

    for (int kt = 0; kt < F / 32; ++kt) {
        const int buf = kt & 1;
        __syncthreads();                       // drains buf's loads (issued kt-1)
        if (kt + 1 < F / 32) {                 // prefetch next tile into other buf
            int k0 = (kt + 1) * 32;
            gl_lds16(aSrc + k0, aDst + (buf ^ 1) * (128 * 32));
            gl_lds16(bSrc + k0, bDst + (buf ^ 1) * (128 * 32));
        }
        const int bo = buf * (128 * 32);
        short8 af[4], bf[2];
#pragma unroll
        for (int mb = 0; mb < 4; ++mb) af[mb] = *(const short8*)(ap[mb] + bo);
#pragma unroll
        for (int nb = 0; nb < 2; ++nb) bf[nb] = *(const short8*)(bp[nb] + bo);
#pragma unroll
        for (int mb = 0; mb < 4; ++mb)
#pragma unroll
            for (int nb = 0; nb < 2; ++nb)
                acc[mb][nb] = __builtin_amdgcn_mfma_f32_16x16x32_bf16(
                    af[mb], bf[nb], acc[mb][nb], 0, 0, 0);
    }

    float s1[4][4], s2[4][4];
#pragma unroll
    for (int mb = 0; mb < 4; ++mb)
#pragma unroll
        for (int r = 0; r < 4; ++r) {
            int row = m0 + wm0 + mb * 16 + q * 4 + r;
            s1[mb][r] = rs1[row];
            s2[mb][r] = rs2[row];
        }
#pragma unroll
    for (int nb = 0; nb < 2; ++nb) {
        int col = n0 + wn0 + nb * 16 + lr;
        float bv = bias[col];
#pragma unroll
        for (int mb = 0; mb < 4; ++mb)
#pragma unroll
            for (int r = 0; r < 4; ++r) {
                int row = m0 + wm0 + mb * 16 + q * 4 + r;
                float v = fmaxf(acc[mb][nb][r] * s1[mb][r] + bv, 0.f) * s2[mb][r];
                Cb[(size_t)row * F + col] = f2bf(v);
            }
    }
}

// ---- bf16 MFMA GEMM, layer 3: z3 = x2' @ Wt3^T, fp32 out, N=64, dbuf ------
__global__ __launch_bounds__(256) void k_gemm3(
        const unsigned short* __restrict__ A,
        const unsigned short* __restrict__ Bt,   // [64 n][F k]
        float* __restrict__ Z) {
    __shared__ short As3[2][64 * 32];
    __shared__ short Bs3[2][64 * 32];
    const int t = threadIdx.x, lane = t & 63, wid = t >> 6;
    const int m0 = blockIdx.x * 64;
    const int lr = lane & 15, q = lane >> 4;

    const int r = wid * 16 + (lane >> 2);
    const int soff = (((lane & 3) ^ ((r >> 1) & 3)) * 8);
    const unsigned short* aSrc = A  + (size_t)(m0 + r) * F + soff;
    const unsigned short* bSrc = Bt + (size_t)r * F + soff;

    const short* ap;
    {
        int m = wid * 16 + lr;
        ap = &As3[0][m * 32 + (q ^ ((m >> 1) & 3)) * 8];
    }
    const short* bp[4];
#pragma unroll
    for (int nb = 0; nb < 4; ++nb) {
        int n = nb * 16 + lr;
        bp[nb] = &Bs3[0][n * 32 + (q ^ ((n >> 1) & 3)) * 8];
    }

    floatx4 acc[4] = {};

    gl_lds16(aSrc, &As3[0][wid * 512]);
    gl_lds16(bSrc, &Bs3[0][wid * 512]);

    for (int kt = 0; kt < F / 32; ++kt) {
        const int buf = kt & 1;
        __syncthreads();
        if (kt + 1 < F / 32) {
            int k0 = (kt + 1) * 32;
            gl_lds16(aSrc + k0, &As3[buf ^ 1][wid * 512]);
            gl_lds16(bSrc + k0, &Bs3[buf ^ 1][wid * 512]);
        }
        const int bo = buf * (64 * 32);
        short8 af = *(const short8*)(ap + bo);
        short8 bf[4];
#pragma unroll
        for (int nb = 0; nb < 4; ++nb) bf[nb] = *(const short8*)(bp[nb] + bo);
#pragma unroll
        for (int nb = 0; nb < 4; ++nb)
            acc[nb] = __builtin_amdgcn_mfma_f32_16x16x32_bf16(af, bf[nb], acc[nb], 0, 0, 0);
    }

#pragma unroll
    for (int nb = 0; nb < 4; ++nb) {
        int col = nb * 16 + lr;
#pragma unroll
        for (int ri = 0; ri < 4; ++ri) {
            int row = m0 + wid * 16 + q * 4 + ri;
            Z[(size_t)row * C3 + col] = acc[nb][ri];
        }
    }
}

// ---- driver ---------------------------------------------------------------

extern "C" void kernel_launch(void* const* d_in, const int* in_sizes, int n_in,
                              void* d_out, int out_size, void* d_ws, size_t ws_size,
                              hipStream_t stream) {
    const float* h   = (const float*)d_in[0];
    const int*   src = (const int*)d_in[1];
    const int*   dst = (const int*)d_in[2];
    const float* W1  = (const float*)d_in[3];
    const float* b1  = (const float*)d_in[4];
    const float* W2  = (const float*)d_in[5];
    const float* b2  = (const float*)d_in[6];
    const float* W3  = (const float*)d_in[7];
    const float* b3  = (const float*)d_in[8];
    float* out = (float*)d_out;

    char* ws = (char*)d_ws;
    int*   deg_out  = (int*)ws;                       ws += MPAD * 4;
    int*   deg_in   = (int*)ws;                       ws += MPAD * 4;
    float* norm_src = (float*)ws;                     ws += MPAD * 4;
    float* norm_dst = (float*)ws;                     ws += MPAD * 4;
    int*   row_ptr  = (int*)ws;                       ws += (NN + 1) * 4;
    int*   cursor   = (int*)ws;                       ws += NN * 4;
    int*   csr_src  = (int*)ws;                       ws += NE * 4;
    ws = (char*)(((size_t)ws + 255) & ~(size_t)255);
    unsigned short* hb   = (unsigned short*)ws;       ws += (size_t)MPAD * F * 2;
    unsigned short* aggb = (unsigned short*)ws;       ws += (size_t)MPAD * F * 2;
    unsigned short* xb   = (unsigned short*)ws;       ws += (size_t)MPAD * F * 2;
    unsigned short* Wt1  = (unsigned short*)ws;       ws += (size_t)F * F * 2;
    unsigned short* Wt2  = (unsigned short*)ws;       ws += (size_t)F * F * 2;
    unsigned short* Wt3  = (unsigned short*)ws;       ws += (size_t)C3 * F * 2;
    float* z3       = (float*)ws;                     // MPAD * C3 * 4

    // CSR build + norms; then merged {bucket | wconv | hcvt}
    hipMemsetAsync(deg_out, 0, 2 * MPAD * sizeof(int), stream);
    k_degree<<<(NE + 255) / 256, 256, 0, stream>>>(src, dst, deg_out, deg_in);
    k_scan<<<1, 1024, 0, stream>>>(deg_in, deg_out, row_ptr, cursor, norm_src, norm_dst);
    k_mid<<<7737, 256, 0, stream>>>(src, dst, cursor, csr_src,
                                    W1, W2, W3, Wt1, Wt2, Wt3,
                                    h, norm_src, hb);

    // layer 1: aggb = Sum hb[src]; xb = bf16(ns.*relu(nd.*(aggb@W1)+b1))
    k_aggb<<<(NN / 16) * 8, 256, 0, stream>>>(hb, row_ptr, csr_src, aggb);
    k_gemm_bf16<<<(MPAD / 128) * (F / 128), 512, 0, stream>>>(aggb, Wt1, b1, norm_dst, norm_src, xb);

    // layer 2
    k_aggb<<<(NN / 16) * 8, 256, 0, stream>>>(xb, row_ptr, csr_src, aggb);
    k_gemm_bf16<<<(MPAD / 128) * (F / 128), 512, 0, stream>>>(aggb, Wt2, b2, norm_dst, norm_src, xb);

    // layer 3: z3 = xb @ W3t ; out = nd.*(A z3) + b3
    k_gemm3<<<MPAD / 64, 256, 0, stream>>>(xb, Wt3, z3);
    k_agg64<<<(NN + 15) / 16, 256, 0, stream>>>(z3, row_ptr, csr_src, norm_dst, b3, out);
}